// Round 7
// baseline (251.416 us; speedup 1.0000x reference)
//
#include <hip/hip_runtime.h>

typedef __bf16 bf16x8 __attribute__((ext_vector_type(8)));
typedef float f32x4 __attribute__((ext_vector_type(4)));

// ---------------- ws layout (float offsets) ----------------
// S overlaps ALLREPS: all_reps is dead before k_mega writes S.
#define WS_S       0         // 2 slabs * 76800 = 153600
#define WS_ALLREPS 0         // 294912 (k_build -> k_gemmB only)
#define WS_APRIME  301056    // 384*768 f32
#define WS_BMAT    595968    // 384*768 f32
#define WS_RELUM1  890880    // 384*384 f32
#define WS_RELUC1  1038336   // 384*384 f32
#define WS_MS      1185792   // 384
#define WS_W2PERM  1186176   // bf16[2*24*768*8] = 147456 f32-words (permuted W2)

#define NMSB  192            // ms blocks (2 rows each)
#define NCE   383
#define PAIRBASE 575         // NMSB + NCE
#define NPAIR 1200           // 600 tiles * 2 hh
#define SLAB  76800          // 600*128

// bank-balanced 16B-chunk swizzle: chunk idx mod 8 bijective per 8-row group
#define SWZ(row,c) (((row)<<2) + ((c) ^ (((row)>>1)&3)))

__device__ __forceinline__ bf16x8 cvt8(float4 a, float4 b) {
  bf16x8 v;
  v[0]=(__bf16)a.x; v[1]=(__bf16)a.y; v[2]=(__bf16)a.z; v[3]=(__bf16)a.w;
  v[4]=(__bf16)b.x; v[5]=(__bf16)b.y; v[6]=(__bf16)b.z; v[7]=(__bf16)b.w;
  return v;
}

__device__ __forceinline__ void gload_lds16(const void* g, void* l) {
  __builtin_amdgcn_global_load_lds(
      (const __attribute__((address_space(1))) void*)g,
      (__attribute__((address_space(3))) void*)l, 16, 0, 0);
}

// K1: all_reps rows 0..383; W2perm blocks 384..431; block 0 zeroes out.
// W2perm layout: [hh][ks][u] 16B units, u=0..767; unit u holds chunk
// q = (u&3)^((u>>3)&3) of local row (u>>2)  -> linear LDS write == SWZ layout.
__global__ __launch_bounds__(256) void k_build(
    const float* __restrict__ seq, const float* __restrict__ spk_emb,
    const float* __restrict__ dummy, const float* __restrict__ W2,
    const int* __restrict__ seg, const int* __restrict__ mstart,
    const int* __restrict__ mend, const int* __restrict__ spk_ids,
    float* __restrict__ all_reps, __bf16* __restrict__ W2perm,
    float* __restrict__ out) {
  int r = blockIdx.x, t = threadIdx.x;
  if (r < 384) {
    if (r == 0) {
      if (t == 0) out[0] = 0.f;
      #pragma unroll
      for (int e = 0; e < 3; ++e) { int k = t + 256*e; all_reps[k] = dummy[k]; }
    } else {
      int m = r - 1;
      int sg = seg[m], st = mstart[m], en = mend[m];
      int sp = spk_ids[sg*512 + st];
      const float* p1 = seq + (size_t)(sg*512 + st)*768;
      const float* p2 = seq + (size_t)(sg*512 + en)*768;
      const float* p3 = spk_emb + (size_t)sp*768;
      #pragma unroll
      for (int e = 0; e < 3; ++e) { int k = t + 256*e; all_reps[r*768+k] = p1[k]+p2[k]+p3[k]; }
    }
  } else {
    int idx = r - 384, hhb = idx / 24, ksb = idx % 24;
    bf16x8* dst = (bf16x8*)W2perm + (size_t)(hhb*24 + ksb)*768;
    #pragma unroll
    for (int e = 0; e < 3; ++e) {
      int u = t + 256*e;
      int row = u >> 2;
      int q = (u & 3) ^ ((u >> 3) & 3);
      const float* sp = W2 + (size_t)(hhb*192 + row)*768 + ksb*32 + q*8;
      float4 f0 = *(const float4*)sp;
      float4 f1 = *(const float4*)(sp + 4);
      dst[u] = cvt8(f0, f1);
    }
  }
}

// K2: C = reps(384x768) @ [A|Bm|m1|c1](768x2304); 64x128 tiles, dbuf LDS
__global__ __launch_bounds__(256) void k_gemmB(
    const float* __restrict__ reps, const float* __restrict__ W1,
    const float* __restrict__ Wm1, const float* __restrict__ Wc1,
    const float* __restrict__ b1, const float* __restrict__ bm1, const float* __restrict__ bc1,
    float* __restrict__ Aprime, float* __restrict__ Bmat,
    float* __restrict__ relu_m1, float* __restrict__ relu_c1) {
  __shared__ bf16x8 lA[2][256];
  __shared__ bf16x8 lB[2][512];
  int nt = blockIdx.x;
  int m0 = blockIdx.y * 64;
  int t = threadIdx.x;
  const float* src; int stride, coloff;
  if (nt < 6)       { src = W1  + (size_t)(nt*128)*1536;      stride = 1536; coloff = 0;   }
  else if (nt < 12) { src = W1  + (size_t)((nt-6)*128)*1536;  stride = 1536; coloff = 768; }
  else if (nt < 15) { src = Wm1 + (size_t)((nt-12)*128)*768;  stride = 768;  coloff = 0;   }
  else              { src = Wc1 + (size_t)((nt-15)*128)*768;  stride = 768;  coloff = 0;   }

  int w = t>>6, l = t&63;
  int wm = w&1, wn = w>>1;
  int lr = l&15, lg = l>>4;

  int p = t>>2, q = t&3;
  const float* pa  = reps + (size_t)(m0+p)*768 + q*8;
  const float* pb0 = src + (size_t)p*stride + coloff + q*8;
  const float* pb1 = src + (size_t)(p+64)*stride + coloff + q*8;
  int ia  = SWZ(p, q);
  int ib0 = SWZ(p, q);
  int ib1 = SWZ(p+64, q);

  float4 a0, a1, b0, b1v, c0, c1v;
  #define G_LOADG(k0) { \
    a0  = *(const float4*)(pa  + (k0)); a1  = *(const float4*)(pa  + (k0) + 4); \
    b0  = *(const float4*)(pb0 + (k0)); b1v = *(const float4*)(pb0 + (k0) + 4); \
    c0  = *(const float4*)(pb1 + (k0)); c1v = *(const float4*)(pb1 + (k0) + 4); }
  #define G_WRITEB(buf) { \
    lA[buf][ia]  = cvt8(a0, a1); \
    lB[buf][ib0] = cvt8(b0, b1v); \
    lB[buf][ib1] = cvt8(c0, c1v); }

  G_LOADG(0);
  G_WRITEB(0);

  f32x4 acc[2][4] = {};
  int cur = 0;

  for (int ks = 0; ks < 24; ++ks) {
    __syncthreads();
    if (ks < 23) G_LOADG((ks+1)*32);
    bf16x8 af[2], bfr[4];
    #pragma unroll
    for (int fa = 0; fa < 2; ++fa) { int row = wm*32 + fa*16 + lr; af[fa] = lA[cur][SWZ(row, lg)]; }
    #pragma unroll
    for (int fb = 0; fb < 4; ++fb) { int row = wn*64 + fb*16 + lr; bfr[fb] = lB[cur][SWZ(row, lg)]; }
    __builtin_amdgcn_s_setprio(1);
    #pragma unroll
    for (int fa = 0; fa < 2; ++fa)
      #pragma unroll
      for (int fb = 0; fb < 4; ++fb)
        acc[fa][fb] = __builtin_amdgcn_mfma_f32_16x16x32_bf16(af[fa], bfr[fb], acc[fa][fb], 0, 0, 0);
    __builtin_amdgcn_s_setprio(0);
    if (ks < 23) G_WRITEB(cur^1);
    cur ^= 1;
  }

  #pragma unroll
  for (int fa = 0; fa < 2; ++fa) {
    #pragma unroll
    for (int fb = 0; fb < 4; ++fb) {
      #pragma unroll
      for (int reg = 0; reg < 4; ++reg) {
        int m = m0 + wm*32 + fa*16 + lg*4 + reg;
        int nl = wn*64 + fb*16 + lr;
        float v = acc[fa][fb][reg];
        if (nt < 6)       { int n = nt*128 + nl;      Aprime[m*768+n]  = v + b1[n]; }
        else if (nt < 12) { int n = (nt-6)*128 + nl;  Bmat[m*768+n]    = v; }
        else if (nt < 15) { int n = (nt-12)*128 + nl; relu_m1[m*384+n] = fmaxf(v + bm1[n], 0.f); }
        else              { int n = (nt-15)*128 + nl; relu_c1[m*384+n] = fmaxf(v + bc1[n], 0.f); }
      }
    }
  }
}

// K3 (mega): [ms 192 | ce 383 | pair 1200] blocks, 256 threads each.
__global__ __launch_bounds__(256, 2) void k_mega(
    const float* __restrict__ Aprime, const float* __restrict__ Bmat,
    const __bf16* __restrict__ W2perm, const float* __restrict__ b2,
    const float* __restrict__ w3, float* __restrict__ S,
    const float* __restrict__ relu_m1, const float* __restrict__ Wm2,
    const float* __restrict__ bm2, const float* __restrict__ Wm3,
    const float* __restrict__ bm3, float* __restrict__ msv,
    const float* __restrict__ relu_c1, const float* __restrict__ Wc2,
    const float* __restrict__ bc2, const int* __restrict__ label,
    float* __restrict__ out) {
  __shared__ char smem[41984];
  __shared__ float part[2][4];
  int bx = blockIdx.x, t = threadIdx.x;

  if (bx >= PAIRBASE) {
    // ---------------- pair branch: 128 pairs (16i x 8j) x 192 h ----------------
    bf16x8 (*lA)[512] = (bf16x8 (*)[512])smem;              // h1 tile, dbuf (16KB)
    bf16x8 (*lB)[768] = (bf16x8 (*)[768])(smem + 16384);    // W2 tile, dbuf (24KB)
    float  (*score)[2] = (float (*)[2])(smem + 40960);      // 1KB
    int pb = bx - PAIRBASE;
    int tile = pb >> 1, hh = pb & 1;
    int ib = (int)((__fsqrt_rn(4.0f*tile + 1.0f) - 1.0f) * 0.5f);
    while ((ib+1)*(ib+2) <= tile) ++ib;
    while (ib*(ib+1) > tile) --ib;
    int jb = tile - ib*(ib+1);
    int i0 = ib*16, j0 = jb*8;

    int w = t>>6, l = t&63;
    int wp = w&1, wh = w>>1;
    int lr = l&15, lg = l>>4;

    // lA staging: thread t stages 2 chunks of pair-row p
    int p = t>>1, qb = (t&1)*2;
    const float* pArow = Aprime + (size_t)(j0 + (p&7))*768 + qb*8;
    const float* pBrow = Bmat   + (size_t)(i0 + (p>>3))*768 + qb*8;
    int idxA0 = SWZ(p, qb), idxA1 = SWZ(p, qb+1);
    // lB staging base (global, pre-permuted)
    const bf16x8* wsrc = (const bf16x8*)W2perm + (size_t)hh*24*768;
    int wbase = t & 192;   // wave-uniform (w*64)

    float4 ga0, ga1, gb0, gb1;

    #define LOADG_A(k0) { \
      ga0 = *(const float4*)(pArow + (k0)); ga1 = *(const float4*)(pArow + (k0) + 4); \
      gb0 = *(const float4*)(pBrow + (k0)); gb1 = *(const float4*)(pBrow + (k0) + 4); }

    #define STAGE_B(ksv, buf) { \
      const bf16x8* gs = wsrc + (size_t)(ksv)*768; \
      gload_lds16(gs +       t, &lB[buf][      wbase]); \
      gload_lds16(gs + 256 + t, &lB[buf][256 + wbase]); \
      gload_lds16(gs + 512 + t, &lB[buf][512 + wbase]); }

    #define WRITEB_A(buf) { \
      float4 r0, r1; \
      r0.x = fmaxf(ga0.x + gb0.x, 0.f); r0.y = fmaxf(ga0.y + gb0.y, 0.f); \
      r0.z = fmaxf(ga0.z + gb0.z, 0.f); r0.w = fmaxf(ga0.w + gb0.w, 0.f); \
      r1.x = fmaxf(ga1.x + gb1.x, 0.f); r1.y = fmaxf(ga1.y + gb1.y, 0.f); \
      r1.z = fmaxf(ga1.z + gb1.z, 0.f); r1.w = fmaxf(ga1.w + gb1.w, 0.f); \
      bf16x8 h01 = cvt8(r0, r1); \
      if ((t&1) == 0) lA[buf][idxA0] = h01; else lA[buf][idxA1] = h01; }

    // NOTE: thread stages chunks qb,qb+1 = 2 16B units from 2 float4-pairs.
    // Re-derive: each thread loads 16 floats of A' and 16 of Bm (4 float4 each).
    float4 ga2, ga3, gb2, gb3;
    #undef LOADG_A
    #define LOADG_A(k0) { \
      ga0 = *(const float4*)(pArow + (k0));     ga1 = *(const float4*)(pArow + (k0) + 4); \
      ga2 = *(const float4*)(pArow + (k0) + 8); ga3 = *(const float4*)(pArow + (k0) + 12); \
      gb0 = *(const float4*)(pBrow + (k0));     gb1 = *(const float4*)(pBrow + (k0) + 4); \
      gb2 = *(const float4*)(pBrow + (k0) + 8); gb3 = *(const float4*)(pBrow + (k0) + 12); }
    #undef WRITEB_A
    #define WRITEB_A(buf) { \
      float4 r0, r1, r2, r3; \
      r0.x = fmaxf(ga0.x + gb0.x, 0.f); r0.y = fmaxf(ga0.y + gb0.y, 0.f); \
      r0.z = fmaxf(ga0.z + gb0.z, 0.f); r0.w = fmaxf(ga0.w + gb0.w, 0.f); \
      r1.x = fmaxf(ga1.x + gb1.x, 0.f); r1.y = fmaxf(ga1.y + gb1.y, 0.f); \
      r1.z = fmaxf(ga1.z + gb1.z, 0.f); r1.w = fmaxf(ga1.w + gb1.w, 0.f); \
      r2.x = fmaxf(ga2.x + gb2.x, 0.f); r2.y = fmaxf(ga2.y + gb2.y, 0.f); \
      r2.z = fmaxf(ga2.z + gb2.z, 0.f); r2.w = fmaxf(ga2.w + gb2.w, 0.f); \
      r3.x = fmaxf(ga3.x + gb3.x, 0.f); r3.y = fmaxf(ga3.y + gb3.y, 0.f); \
      r3.z = fmaxf(ga3.z + gb3.z, 0.f); r3.w = fmaxf(ga3.w + gb3.w, 0.f); \
      lA[buf][idxA0] = cvt8(r0, r1); \
      lA[buf][idxA1] = cvt8(r2, r3); }

    LOADG_A(0);
    STAGE_B(0, 0);
    WRITEB_A(0);

    f32x4 acc[4][6] = {};
    int cur = 0;

    for (int ks = 0; ks < 24; ++ks) {
      __syncthreads();                        // buf[cur] ready (barrier drains vmcnt)
      if (ks < 23) { STAGE_B(ks+1, cur^1); LOADG_A((ks+1)*32); }
      bf16x8 af[4], bfr[6];
      #pragma unroll
      for (int fp = 0; fp < 4; ++fp) { int row = wp*64 + fp*16 + lr; af[fp] = lA[cur][SWZ(row, lg)]; }
      #pragma unroll
      for (int fh = 0; fh < 6; ++fh) { int row = wh*96 + fh*16 + lr; bfr[fh] = lB[cur][SWZ(row, lg)]; }
      __builtin_amdgcn_s_setprio(1);
      #pragma unroll
      for (int fp = 0; fp < 4; ++fp)
        #pragma unroll
        for (int fh = 0; fh < 6; ++fh)
          acc[fp][fh] = __builtin_amdgcn_mfma_f32_16x16x32_bf16(af[fp], bfr[fh], acc[fp][fh], 0, 0, 0);
      __builtin_amdgcn_s_setprio(0);
      if (ks < 23) WRITEB_A(cur^1);           // vmcnt wait for ga/gb lands after MFMA
      cur ^= 1;
    }

    // epilogue: partial score over this wave's 96 h
    float sacc[4][4] = {};
    #pragma unroll
    for (int fh = 0; fh < 6; ++fh) {
      int hcol = hh*192 + wh*96 + fh*16 + lr;
      float bb = b2[hcol], ww = w3[hcol];
      #pragma unroll
      for (int fp = 0; fp < 4; ++fp)
        #pragma unroll
        for (int reg = 0; reg < 4; ++reg)
          sacc[fp][reg] += fmaxf(acc[fp][fh][reg] + bb, 0.f) * ww;
    }
    #pragma unroll
    for (int fp = 0; fp < 4; ++fp) {
      #pragma unroll
      for (int reg = 0; reg < 4; ++reg) {
        float v = sacc[fp][reg];
        v += __shfl_xor(v, 1); v += __shfl_xor(v, 2);
        v += __shfl_xor(v, 4); v += __shfl_xor(v, 8);
        if (lr == 0) score[wp*64 + fp*16 + lg*4 + reg][wh] = v;
      }
    }
    __syncthreads();
    if (t < 128) S[(size_t)hh*SLAB + tile*128 + t] = score[t][0] + score[t][1];
  } else if (bx < NMSB) {
    // ---------------- ms branch: 2 mention rows ----------------
    float* xs = (float*)smem;   // [2][384]
    int r0 = bx*2;
    const float4* srcv = (const float4*)(relu_m1 + (size_t)r0*384);
    if (t < 192) ((float4*)xs)[t] = srcv[t];
    __syncthreads();
    float a[2] = {};
    if (t < 192) {
      const float4* wv = (const float4*)(Wm2 + (size_t)t*384);
      for (int k = 0; k < 96; ++k) {
        float4 wq = wv[k];
        #pragma unroll
        for (int rr = 0; rr < 2; ++rr) {
          float4 xq = *(const float4*)&xs[rr*384 + k*4];
          a[rr] += wq.x*xq.x + wq.y*xq.y + wq.z*xq.z + wq.w*xq.w;
        }
      }
    }
    float wm3 = (t < 192) ? Wm3[t] : 0.f, bb = (t < 192) ? bm2[t] : 0.f;
    #pragma unroll
    for (int rr = 0; rr < 2; ++rr) {
      float c = (t < 192) ? fmaxf(a[rr] + bb, 0.f) * wm3 : 0.f;
      c += __shfl_xor(c, 1);  c += __shfl_xor(c, 2);  c += __shfl_xor(c, 4);
      c += __shfl_xor(c, 8);  c += __shfl_xor(c, 16); c += __shfl_xor(c, 32);
      if ((t&63) == 0) part[rr][t>>6] = c;
    }
    __syncthreads();
    if (t < 2) msv[r0+t] = part[t][0] + part[t][1] + part[t][2] + part[t][3] + bm3[0];
  } else {
    // ---------------- ce branch: one mention ----------------
    float* lg = (float*)smem;
    int m = bx - NMSB;
    if (t < 18) {
      const float4* xv = (const float4*)(relu_c1 + (size_t)(m+1)*384);
      const float4* wv = (const float4*)(Wc2 + (size_t)t*384);
      float d = 0.f;
      for (int k = 0; k < 96; ++k) {
        float4 a = xv[k], b = wv[k];
        d += a.x*b.x + a.y*b.y + a.z*b.z + a.w*b.w;
      }
      lg[t] = d + bc2[t];
    }
    __syncthreads();
    if (t == 0) {
      float sum = 0.f;
      for (int c = 0; c < 18; ++c) sum += __expf(lg[c]);
      atomicAdd(out, __logf(sum) - lg[label[m]]);
    }
  }
}

// K4: per-row softmax epilogue + nll. 383 blocks (i=bid+1), 64 threads.
__global__ __launch_bounds__(64) void k_epi(
    const float* __restrict__ S, const float* __restrict__ ms,
    const float* __restrict__ b3, const int* __restrict__ lfirst,
    float* __restrict__ out) {
  int i = blockIdx.x + 1;
  int lane = threadIdx.x;
  int ibb = i >> 4, r = i & 15;
  int f = lfirst[i-1];
  float bb3 = b3[0];
  float esum = 0.f, smf = 0.f;
  int tri = ibb*(ibb+1);
  for (int j = lane; j < i; j += 64) {
    int jbb = j >> 3;
    int idx = (tri + jbb)*128 + r*8 + (j&7);
    float s = S[idx] + S[SLAB + idx] + bb3 + ms[j];
    esum += __expf(s);
    if (j == f) smf = s;
  }
  esum += __shfl_xor(esum, 1);  esum += __shfl_xor(esum, 2);
  esum += __shfl_xor(esum, 4);  esum += __shfl_xor(esum, 8);
  esum += __shfl_xor(esum, 16); esum += __shfl_xor(esum, 32);
  smf += __shfl_xor(smf, 1);  smf += __shfl_xor(smf, 2);
  smf += __shfl_xor(smf, 4);  smf += __shfl_xor(smf, 8);
  smf += __shfl_xor(smf, 16); smf += __shfl_xor(smf, 32);
  if (lane == 0) atomicAdd(out, __logf(esum) - smf);
}

extern "C" void kernel_launch(void* const* d_in, const int* in_sizes, int n_in,
                              void* d_out, int out_size, void* d_ws, size_t ws_size,
                              hipStream_t stream) {
  (void)in_sizes; (void)n_in; (void)out_size; (void)ws_size;
  const float* seq   = (const float*)d_in[0];
  const float* spk   = (const float*)d_in[1];
  const float* dummy = (const float*)d_in[2];
  const float* W1    = (const float*)d_in[3];
  const float* b1    = (const float*)d_in[4];
  const float* W2    = (const float*)d_in[5];
  const float* b2    = (const float*)d_in[6];
  const float* W3    = (const float*)d_in[7];
  const float* b3    = (const float*)d_in[8];
  const float* Wm1   = (const float*)d_in[9];
  const float* bm1   = (const float*)d_in[10];
  const float* Wm2   = (const float*)d_in[11];
  const float* bm2   = (const float*)d_in[12];
  const float* Wm3   = (const float*)d_in[13];
  const float* bm3   = (const float*)d_in[14];
  const float* Wc1   = (const float*)d_in[15];
  const float* bc1   = (const float*)d_in[16];
  const float* Wc2   = (const float*)d_in[17];
  const float* bc2   = (const float*)d_in[18];
  const int* seg     = (const int*)d_in[19];
  const int* mstart  = (const int*)d_in[20];
  const int* mend    = (const int*)d_in[21];
  const int* spk_ids = (const int*)d_in[22];
  const int* lfirst  = (const int*)d_in[23];
  const int* clabel  = (const int*)d_in[25];

  float* ws = (float*)d_ws;
  float* S        = ws + WS_S;
  float* all_reps = ws + WS_ALLREPS;
  float* Aprime   = ws + WS_APRIME;
  float* Bmat     = ws + WS_BMAT;
  float* relu_m1  = ws + WS_RELUM1;
  float* relu_c1  = ws + WS_RELUC1;
  float* msv      = ws + WS_MS;
  __bf16* W2perm  = (__bf16*)(ws + WS_W2PERM);
  float* out      = (float*)d_out;

  k_build<<<432, 256, 0, stream>>>(seq, spk, dummy, W2, seg, mstart, mend, spk_ids, all_reps, W2perm, out);
  k_gemmB<<<dim3(18,6), 256, 0, stream>>>(all_reps, W1, Wm1, Wc1, b1, bm1, bc1, Aprime, Bmat, relu_m1, relu_c1);
  k_mega<<<PAIRBASE + NPAIR, 256, 0, stream>>>(Aprime, Bmat, W2perm, b2, W3, S,
                                               relu_m1, Wm2, bm2, Wm3, bm3, msv,
                                               relu_c1, Wc2, bc2, clabel, out);
  k_epi<<<383, 64, 0, stream>>>(S, msv, b3, lfirst, out);
}

// Round 8
// 234.877 us; speedup vs baseline: 1.0704x; 1.0704x over previous
//
#include <hip/hip_runtime.h>

typedef __bf16 bf16x8 __attribute__((ext_vector_type(8)));
typedef float f32x4 __attribute__((ext_vector_type(4)));

// ---------------- ws layout (float offsets) ----------------
#define WS_S       0         // 3 slabs * 75264 = 225792
#define WS_APRIME  301056    // 384*768 f32
#define WS_BMAT    595968    // 384*768 f32
#define WS_RELUM1  890880    // 384*384 f32
#define WS_RELUC1  1038336   // 384*384 f32
#define WS_MS      1185792   // 384
#define WS_W2BF    1186176   // bf16[384*768] = 147456 f32-words

#define NMSB  192
#define NCE   383
#define PAIRBASE 575         // NMSB + NCE
#define NTILE 1176           // 8x8 lower-tri tiles
#define NPAIRB 3528          // NTILE * 3 hh
#define SLAB  75264          // 1176*64

// bank-balanced 16B-chunk swizzle: chunk idx mod 8 bijective per 8-row group
#define SWZ(row,c) (((row)<<2) + ((c) ^ (((row)>>1)&3)))

__device__ __forceinline__ bf16x8 cvt8(float4 a, float4 b) {
  bf16x8 v;
  v[0]=(__bf16)a.x; v[1]=(__bf16)a.y; v[2]=(__bf16)a.z; v[3]=(__bf16)a.w;
  v[4]=(__bf16)b.x; v[5]=(__bf16)b.y; v[6]=(__bf16)b.z; v[7]=(__bf16)b.w;
  return v;
}

// K1 (fused): gemm blocks (0..107) with in-loop reps gather; W2bf build (108..155).
__global__ __launch_bounds__(256) void k_gb(
    const float* __restrict__ seq, const float* __restrict__ spk_emb,
    const float* __restrict__ dummy, const float* __restrict__ W2,
    const int* __restrict__ seg, const int* __restrict__ mstart,
    const int* __restrict__ mend, const int* __restrict__ spk_ids,
    const float* __restrict__ W1,
    const float* __restrict__ Wm1, const float* __restrict__ Wc1,
    const float* __restrict__ b1, const float* __restrict__ bm1, const float* __restrict__ bc1,
    float* __restrict__ Aprime, float* __restrict__ Bmat,
    float* __restrict__ relu_m1, float* __restrict__ relu_c1,
    __bf16* __restrict__ W2bf, float* __restrict__ out) {
  int bx = blockIdx.x, t = threadIdx.x;

  if (bx >= 108) {
    // ---- W2bf build: 48 blocks x 8 rows ----
    int r = bx - 108;
    if (r == 0 && t == 0) out[0] = 0.f;
    #pragma unroll
    for (int rr = 0; rr < 8; ++rr) {
      int base = (r*8 + rr)*768;
      #pragma unroll
      for (int e = 0; e < 3; ++e) { int k = t + 256*e; W2bf[base+k] = (__bf16)W2[base+k]; }
    }
    return;
  }

  __shared__ bf16x8 lA[2][256];
  __shared__ bf16x8 lB[2][512];
  int nt = bx % 18;
  int m0 = (bx / 18) * 64;
  const float* src; int stride, coloff;
  if (nt < 6)       { src = W1  + (size_t)(nt*128)*1536;      stride = 1536; coloff = 0;   }
  else if (nt < 12) { src = W1  + (size_t)((nt-6)*128)*1536;  stride = 1536; coloff = 768; }
  else if (nt < 15) { src = Wm1 + (size_t)((nt-12)*128)*768;  stride = 768;  coloff = 0;   }
  else              { src = Wc1 + (size_t)((nt-15)*128)*768;  stride = 768;  coloff = 0;   }

  int w = t>>6, l = t&63;
  int wm = w&1, wn = w>>1;
  int lr = l&15, lg = l>>4;

  int p = t>>2, q = t&3;
  // A-side gather pointers (reps row m0+p computed on the fly)
  int row = m0 + p;
  const float *pa1, *pa2, *pa3;
  bool rz = (row == 0);
  if (rz) { pa1 = dummy + q*8; pa2 = pa1; pa3 = pa1; }
  else {
    int m = row - 1;
    int sg = seg[m], st = mstart[m], en = mend[m];
    int sp = spk_ids[sg*512 + st];
    pa1 = seq + (size_t)(sg*512 + st)*768 + q*8;
    pa2 = seq + (size_t)(sg*512 + en)*768 + q*8;
    pa3 = spk_emb + (size_t)sp*768 + q*8;
  }
  const float* pb0 = src + (size_t)p*stride + coloff + q*8;
  const float* pb1 = src + (size_t)(p+64)*stride + coloff + q*8;
  int ia  = SWZ(p, q);
  int ib0 = SWZ(p, q);
  int ib1 = SWZ(p+64, q);

  float4 a0, a1, b0, b1v, c0, c1v;
  #define G_LOADG(k0) { \
    float4 x0 = *(const float4*)(pa1 + (k0)), x1 = *(const float4*)(pa1 + (k0) + 4); \
    float4 y0 = *(const float4*)(pa2 + (k0)), y1 = *(const float4*)(pa2 + (k0) + 4); \
    float4 z0 = *(const float4*)(pa3 + (k0)), z1 = *(const float4*)(pa3 + (k0) + 4); \
    if (rz) { a0 = x0; a1 = x1; } \
    else { \
      a0.x = x0.x+y0.x+z0.x; a0.y = x0.y+y0.y+z0.y; a0.z = x0.z+y0.z+z0.z; a0.w = x0.w+y0.w+z0.w; \
      a1.x = x1.x+y1.x+z1.x; a1.y = x1.y+y1.y+z1.y; a1.z = x1.z+y1.z+z1.z; a1.w = x1.w+y1.w+z1.w; } \
    b0  = *(const float4*)(pb0 + (k0)); b1v = *(const float4*)(pb0 + (k0) + 4); \
    c0  = *(const float4*)(pb1 + (k0)); c1v = *(const float4*)(pb1 + (k0) + 4); }
  #define G_WRITEB(buf) { \
    lA[buf][ia]  = cvt8(a0, a1); \
    lB[buf][ib0] = cvt8(b0, b1v); \
    lB[buf][ib1] = cvt8(c0, c1v); }

  G_LOADG(0);
  G_WRITEB(0);

  f32x4 acc[2][4] = {};
  int cur = 0;

  for (int ks = 0; ks < 24; ++ks) {
    __syncthreads();
    if (ks < 23) G_LOADG((ks+1)*32);
    bf16x8 af[2], bfr[4];
    #pragma unroll
    for (int fa = 0; fa < 2; ++fa) { int rr = wm*32 + fa*16 + lr; af[fa] = lA[cur][SWZ(rr, lg)]; }
    #pragma unroll
    for (int fb = 0; fb < 4; ++fb) { int rr = wn*64 + fb*16 + lr; bfr[fb] = lB[cur][SWZ(rr, lg)]; }
    __builtin_amdgcn_s_setprio(1);
    #pragma unroll
    for (int fa = 0; fa < 2; ++fa)
      #pragma unroll
      for (int fb = 0; fb < 4; ++fb)
        acc[fa][fb] = __builtin_amdgcn_mfma_f32_16x16x32_bf16(af[fa], bfr[fb], acc[fa][fb], 0, 0, 0);
    __builtin_amdgcn_s_setprio(0);
    if (ks < 23) G_WRITEB(cur^1);
    cur ^= 1;
  }

  #pragma unroll
  for (int fa = 0; fa < 2; ++fa) {
    #pragma unroll
    for (int fb = 0; fb < 4; ++fb) {
      #pragma unroll
      for (int reg = 0; reg < 4; ++reg) {
        int m = m0 + wm*32 + fa*16 + lg*4 + reg;
        int nl = wn*64 + fb*16 + lr;
        float v = acc[fa][fb][reg];
        if (nt < 6)       { int n = nt*128 + nl;      Aprime[m*768+n]  = v + b1[n]; }
        else if (nt < 12) { int n = (nt-6)*128 + nl;  Bmat[m*768+n]    = v; }
        else if (nt < 15) { int n = (nt-12)*128 + nl; relu_m1[m*384+n] = fmaxf(v + bm1[n], 0.f); }
        else              { int n = (nt-15)*128 + nl; relu_c1[m*384+n] = fmaxf(v + bc1[n], 0.f); }
      }
    }
  }
}

// K2 (mega): [ms 192 | ce 383 | pair 3528] blocks, 256 threads, 4 blocks/CU.
__global__ __launch_bounds__(256, 4) void k_mega(
    const float* __restrict__ Aprime, const float* __restrict__ Bmat,
    const __bf16* __restrict__ W2bf, const float* __restrict__ b2,
    const float* __restrict__ w3, float* __restrict__ S,
    const float* __restrict__ relu_m1, const float* __restrict__ Wm2,
    const float* __restrict__ bm2, const float* __restrict__ Wm3,
    const float* __restrict__ bm3, float* __restrict__ msv,
    const float* __restrict__ relu_c1, const float* __restrict__ Wc2,
    const float* __restrict__ bc2, const int* __restrict__ label,
    float* __restrict__ out) {
  __shared__ char smem[25088];
  __shared__ float part[2][4];
  int bx = blockIdx.x, t = threadIdx.x;

  if (bx >= PAIRBASE) {
    // ---------------- pair branch: 64 pairs (8i x 8j) x 128 h ----------------
    bf16x8 (*lA)[256] = (bf16x8 (*)[256])smem;              // h1 tile, dbuf (8KB)
    bf16x8 (*lB)[512] = (bf16x8 (*)[512])(smem + 8192);     // W2 tile, dbuf (16KB)
    float  (*score)[2] = (float (*)[2])(smem + 24576);      // 512B
    int pb = bx - PAIRBASE;
    int tt = pb / 3, hh = pb - tt*3;
    int ib = (int)((__fsqrt_rn(8.0f*tt + 1.0f) - 1.0f) * 0.5f);
    while ((ib+1)*(ib+2)/2 <= tt) ++ib;
    while (ib*(ib+1)/2 > tt) --ib;
    int jb = tt - ib*(ib+1)/2;
    int i0 = ib*8, j0 = jb*8, h0 = hh*128;

    int w = t>>6, l = t&63;
    int wp = w&1, wh = w>>1;
    int lr = l&15, lg = l>>4;

    // lA staging: 1 chunk/thread: pair-row p, chunk q
    int p = t>>2, q = t&3;
    const float* pArow = Aprime + (size_t)(j0 + (p&7))*768 + q*8;
    const float* pBrow = Bmat   + (size_t)(i0 + (p>>3))*768 + q*8;
    int idxA = SWZ(p, q);
    // lB staging: 2 chunks/thread
    const __bf16* pW0; const __bf16* pW1; int idxW0, idxW1;
    { int u0 = t, u1 = t + 256;
      pW0 = W2bf + (size_t)(h0 + (u0>>2))*768 + (u0&3)*8;
      pW1 = W2bf + (size_t)(h0 + (u1>>2))*768 + (u1&3)*8;
      idxW0 = SWZ(u0>>2, u0&3); idxW1 = SWZ(u1>>2, u1&3); }

    float4 ga0, ga1, gb0, gb1;
    bf16x8 gw0, gw1;

    #define LOADG(k0) { \
      ga0 = *(const float4*)(pArow + (k0)); ga1 = *(const float4*)(pArow + (k0) + 4); \
      gb0 = *(const float4*)(pBrow + (k0)); gb1 = *(const float4*)(pBrow + (k0) + 4); \
      gw0 = *(const bf16x8*)(pW0 + (k0));   gw1 = *(const bf16x8*)(pW1 + (k0)); }

    #define WRITEB(buf) { \
      float4 r0, r1; \
      r0.x = fmaxf(ga0.x + gb0.x, 0.f); r0.y = fmaxf(ga0.y + gb0.y, 0.f); \
      r0.z = fmaxf(ga0.z + gb0.z, 0.f); r0.w = fmaxf(ga0.w + gb0.w, 0.f); \
      r1.x = fmaxf(ga1.x + gb1.x, 0.f); r1.y = fmaxf(ga1.y + gb1.y, 0.f); \
      r1.z = fmaxf(ga1.z + gb1.z, 0.f); r1.w = fmaxf(ga1.w + gb1.w, 0.f); \
      lA[buf][idxA] = cvt8(r0, r1); \
      lB[buf][idxW0] = gw0; lB[buf][idxW1] = gw1; }

    LOADG(0);
    WRITEB(0);

    f32x4 acc[2][4] = {};
    int cur = 0;

    for (int ks = 0; ks < 24; ++ks) {
      __syncthreads();                 // buf[cur] ready
      if (ks < 23) LOADG((ks+1)*32);   // latency hides under ds_read + MFMA
      bf16x8 af[2], bfr[4];
      #pragma unroll
      for (int fp = 0; fp < 2; ++fp) { int rr = wp*32 + fp*16 + lr; af[fp] = lA[cur][SWZ(rr, lg)]; }
      #pragma unroll
      for (int fh = 0; fh < 4; ++fh) { int rr = wh*64 + fh*16 + lr; bfr[fh] = lB[cur][SWZ(rr, lg)]; }
      __builtin_amdgcn_s_setprio(1);
      #pragma unroll
      for (int fp = 0; fp < 2; ++fp)
        #pragma unroll
        for (int fh = 0; fh < 4; ++fh)
          acc[fp][fh] = __builtin_amdgcn_mfma_f32_16x16x32_bf16(af[fp], bfr[fh], acc[fp][fh], 0, 0, 0);
      __builtin_amdgcn_s_setprio(0);
      if (ks < 23) WRITEB(cur^1);      // vmcnt wait lands after MFMA phase
      cur ^= 1;
    }

    // epilogue: partial score over this wave's 64 h
    float sacc[2][4] = {};
    #pragma unroll
    for (int fh = 0; fh < 4; ++fh) {
      int hcol = h0 + wh*64 + fh*16 + lr;
      float bb = b2[hcol], ww = w3[hcol];
      #pragma unroll
      for (int fp = 0; fp < 2; ++fp)
        #pragma unroll
        for (int reg = 0; reg < 4; ++reg)
          sacc[fp][reg] += fmaxf(acc[fp][fh][reg] + bb, 0.f) * ww;
    }
    #pragma unroll
    for (int fp = 0; fp < 2; ++fp) {
      #pragma unroll
      for (int reg = 0; reg < 4; ++reg) {
        float v = sacc[fp][reg];
        v += __shfl_xor(v, 1); v += __shfl_xor(v, 2);
        v += __shfl_xor(v, 4); v += __shfl_xor(v, 8);
        if (lr == 0) score[wp*32 + fp*16 + lg*4 + reg][wh] = v;
      }
    }
    __syncthreads();
    if (t < 64) S[(size_t)hh*SLAB + tt*64 + t] = score[t][0] + score[t][1];
  } else if (bx < NMSB) {
    // ---------------- ms branch: 2 mention rows ----------------
    float* xs = (float*)smem;   // [2][384]
    int r0 = bx*2;
    const float4* srcv = (const float4*)(relu_m1 + (size_t)r0*384);
    if (t < 192) ((float4*)xs)[t] = srcv[t];
    __syncthreads();
    float a[2] = {};
    if (t < 192) {
      const float4* wv = (const float4*)(Wm2 + (size_t)t*384);
      for (int k = 0; k < 96; ++k) {
        float4 wq = wv[k];
        #pragma unroll
        for (int rr = 0; rr < 2; ++rr) {
          float4 xq = *(const float4*)&xs[rr*384 + k*4];
          a[rr] += wq.x*xq.x + wq.y*xq.y + wq.z*xq.z + wq.w*xq.w;
        }
      }
    }
    float wm3 = (t < 192) ? Wm3[t] : 0.f, bb = (t < 192) ? bm2[t] : 0.f;
    #pragma unroll
    for (int rr = 0; rr < 2; ++rr) {
      float c = (t < 192) ? fmaxf(a[rr] + bb, 0.f) * wm3 : 0.f;
      c += __shfl_xor(c, 1);  c += __shfl_xor(c, 2);  c += __shfl_xor(c, 4);
      c += __shfl_xor(c, 8);  c += __shfl_xor(c, 16); c += __shfl_xor(c, 32);
      if ((t&63) == 0) part[rr][t>>6] = c;
    }
    __syncthreads();
    if (t < 2) msv[r0+t] = part[t][0] + part[t][1] + part[t][2] + part[t][3] + bm3[0];
  } else {
    // ---------------- ce branch: one mention ----------------
    float* lg = (float*)smem;
    int m = bx - NMSB;
    if (t < 18) {
      const float4* xv = (const float4*)(relu_c1 + (size_t)(m+1)*384);
      const float4* wv = (const float4*)(Wc2 + (size_t)t*384);
      float d = 0.f;
      for (int k = 0; k < 96; ++k) {
        float4 a = xv[k], b = wv[k];
        d += a.x*b.x + a.y*b.y + a.z*b.z + a.w*b.w;
      }
      lg[t] = d + bc2[t];
    }
    __syncthreads();
    if (t == 0) {
      float sum = 0.f;
      for (int c = 0; c < 18; ++c) sum += __expf(lg[c]);
      atomicAdd(out, __logf(sum) - lg[label[m]]);
    }
  }
}

// K3: per-row softmax epilogue + nll. 383 blocks (i=bid+1), 64 threads.
__global__ __launch_bounds__(64) void k_epi(
    const float* __restrict__ S, const float* __restrict__ ms,
    const float* __restrict__ b3, const int* __restrict__ lfirst,
    float* __restrict__ out) {
  int i = blockIdx.x + 1;
  int lane = threadIdx.x;
  int ibb = i >> 3, r = i & 7;
  int f = lfirst[i-1];
  float bb3 = b3[0];
  float esum = 0.f, smf = 0.f;
  int tri = ibb*(ibb+1)/2;
  for (int j = lane; j < i; j += 64) {
    int jbb = j >> 3;
    int idx = (tri + jbb)*64 + r*8 + (j&7);
    float s = S[idx] + S[SLAB + idx] + S[2*SLAB + idx] + bb3 + ms[j];
    esum += __expf(s);
    if (j == f) smf = s;
  }
  esum += __shfl_xor(esum, 1);  esum += __shfl_xor(esum, 2);
  esum += __shfl_xor(esum, 4);  esum += __shfl_xor(esum, 8);
  esum += __shfl_xor(esum, 16); esum += __shfl_xor(esum, 32);
  smf += __shfl_xor(smf, 1);  smf += __shfl_xor(smf, 2);
  smf += __shfl_xor(smf, 4);  smf += __shfl_xor(smf, 8);
  smf += __shfl_xor(smf, 16); smf += __shfl_xor(smf, 32);
  if (lane == 0) atomicAdd(out, __logf(esum) - smf);
}

extern "C" void kernel_launch(void* const* d_in, const int* in_sizes, int n_in,
                              void* d_out, int out_size, void* d_ws, size_t ws_size,
                              hipStream_t stream) {
  (void)in_sizes; (void)n_in; (void)out_size; (void)ws_size;
  const float* seq   = (const float*)d_in[0];
  const float* spk   = (const float*)d_in[1];
  const float* dummy = (const float*)d_in[2];
  const float* W1    = (const float*)d_in[3];
  const float* b1    = (const float*)d_in[4];
  const float* W2    = (const float*)d_in[5];
  const float* b2    = (const float*)d_in[6];
  const float* W3    = (const float*)d_in[7];
  const float* b3    = (const float*)d_in[8];
  const float* Wm1   = (const float*)d_in[9];
  const float* bm1   = (const float*)d_in[10];
  const float* Wm2   = (const float*)d_in[11];
  const float* bm2   = (const float*)d_in[12];
  const float* Wm3   = (const float*)d_in[13];
  const float* bm3   = (const float*)d_in[14];
  const float* Wc1   = (const float*)d_in[15];
  const float* bc1   = (const float*)d_in[16];
  const float* Wc2   = (const float*)d_in[17];
  const float* bc2   = (const float*)d_in[18];
  const int* seg     = (const int*)d_in[19];
  const int* mstart  = (const int*)d_in[20];
  const int* mend    = (const int*)d_in[21];
  const int* spk_ids = (const int*)d_in[22];
  const int* lfirst  = (const int*)d_in[23];
  const int* clabel  = (const int*)d_in[25];

  float* ws = (float*)d_ws;
  float* S        = ws + WS_S;
  float* Aprime   = ws + WS_APRIME;
  float* Bmat     = ws + WS_BMAT;
  float* relu_m1  = ws + WS_RELUM1;
  float* relu_c1  = ws + WS_RELUC1;
  float* msv      = ws + WS_MS;
  __bf16* W2bf    = (__bf16*)(ws + WS_W2BF);
  float* out      = (float*)d_out;

  k_gb<<<156, 256, 0, stream>>>(seq, spk, dummy, W2, seg, mstart, mend, spk_ids,
                                W1, Wm1, Wc1, b1, bm1, bc1,
                                Aprime, Bmat, relu_m1, relu_c1, W2bf, out);
  k_mega<<<PAIRBASE + NPAIRB, 256, 0, stream>>>(Aprime, Bmat, W2bf, b2, W3, S,
                                                relu_m1, Wm2, bm2, Wm3, bm3, msv,
                                                relu_c1, Wc2, bc2, clabel, out);
  k_epi<<<383, 64, 0, stream>>>(S, msv, b3, lfirst, out);
}